// Round 5
// baseline (7669.181 us; speedup 1.0000x reference)
//
#include <hip/hip_runtime.h>
#include <math.h>

#define NBLK 496
#define NTHR 256
#define TSTEPS 48

// ---------------- workspace layout (float offsets) ----------------
#define OFF_W4IH0 0                    // [128 k4][1024 g][4 k]  (K=512)
#define OFF_W4HH0 524288               // [64][1024][4]          (K=256)
#define OFF_W4IH1 786432               // [64][1024][4]
#define OFF_W4HH1 1048576              // [64][1024][4]
#define OFF_BSUM0 1310720              // [1024]
#define OFF_BSUM1 1311744              // [1024]
#define OFF_APART 1312768              // [8 ks][64 b][1024 g]  layer-0 emb partials
#define OFF_PARTA 1837056              // [64 b][1024 g]  Whh0 @ h0(t-1)
#define OFF_PARTB 1902592              // [64 b][1024 g]  Whh1 @ h1(t-1)
#define OFF_H0    1968128              // [64][256]
#define OFF_H1    1984512              // [64][256]
#define OFF_C0    2000896              // [2][64][256] parity
#define OFF_C1    2033664              // [64][256] (t=0 seed; c1 lives in B regs after)
#define OFF_FLOAT_END 2050048
// bytes after floats: argkey u64[4*64*8] (16384), key2 u64[64*512] (262144),
// flags u32[3840] (15360)

// flags (u32 offsets)
#define F_RED  0      // 64 flags, stride 32 (posted by R, polled by A)
#define F_CELL 2048   // 8 lines x 32: per-bg [0..7]=A ks, [8..11]=PA ps, [12..15]=PB ps, [16..19]=H0 hq
#define F_H1F  2304   // 32 flags, stride 32 (posted by B, polled by D + pB)
#define F_ARG  3328   // 512 dense (400 used; 400..511 preset huge)
#define NFLAGS 3840

// ---- coherent (sc1, device-visible) accessors ----
__device__ __forceinline__ float ld_coh(const float* p) {
  return __hip_atomic_load((float*)p, __ATOMIC_RELAXED, __HIP_MEMORY_SCOPE_AGENT);
}
__device__ __forceinline__ void st_coh(float* p, float v) {
  __hip_atomic_store(p, v, __ATOMIC_RELAXED, __HIP_MEMORY_SCOPE_AGENT);
}
__device__ __forceinline__ unsigned long long ld_coh64(const unsigned long long* p) {
  return __hip_atomic_load((unsigned long long*)p, __ATOMIC_RELAXED, __HIP_MEMORY_SCOPE_AGENT);
}
__device__ __forceinline__ void st_coh64(unsigned long long* p, unsigned long long v) {
  __hip_atomic_store(p, v, __ATOMIC_RELAXED, __HIP_MEMORY_SCOPE_AGENT);
}
__device__ __forceinline__ unsigned ld_cohu(const unsigned* p) {
  return __hip_atomic_load((unsigned*)p, __ATOMIC_RELAXED, __HIP_MEMORY_SCOPE_AGENT);
}
__device__ __forceinline__ void st_cohu(unsigned* p, unsigned v) {
  __hip_atomic_store(p, v, __ATOMIC_RELAXED, __HIP_MEMORY_SCOPE_AGENT);
}
__device__ __forceinline__ float sigf(float x) { return 1.0f / (1.0f + expf(-x)); }

// publish: drain this block's stores to the coherence point, then one lane posts.
__device__ __forceinline__ void post_u32(unsigned* f, unsigned val) {
  __asm__ __volatile__("" ::: "memory");
  __builtin_amdgcn_s_waitcnt(0);
  __syncthreads();
  if (threadIdx.x == 0) st_cohu(f, val);
  __asm__ __volatile__("" ::: "memory");
}

// ---- K1: states, bias sums, argkey/key2/flags init ----
__global__ void lstm_init_kernel(const float* enc, const float* Wh, const float* bh,
                                 const float* Wc, const float* bc,
                                 const float* bih0, const float* bhh0,
                                 const float* bih1, const float* bhh1,
                                 float* ws, unsigned long long* argkey,
                                 unsigned long long* key2, unsigned* flags) {
  const int tid = threadIdx.x, blk = blockIdx.x;
  if (blk < 64) {
    __shared__ float el[256];
    el[tid] = enc[blk * 256 + tid];
    __syncthreads();
    const float4* el4 = (const float4*)el;
    const float4* wh4 = (const float4*)(Wh + tid * 256);
    const float4* wc4 = (const float4*)(Wc + tid * 256);
    float ah = bh[tid], ac = bc[tid];
#pragma unroll 4
    for (int f = 0; f < 64; ++f) {
      float4 x = el4[f], a = wh4[f], b = wc4[f];
      ah = fmaf(a.x, x.x, fmaf(a.y, x.y, fmaf(a.z, x.z, fmaf(a.w, x.w, ah))));
      ac = fmaf(b.x, x.x, fmaf(b.y, x.y, fmaf(b.z, x.z, fmaf(b.w, x.w, ac))));
    }
    ws[OFF_H0 + blk * 256 + tid] = ah;
    ws[OFF_H1 + blk * 256 + tid] = ah;
    ws[OFF_C0 + blk * 256 + tid] = ac;   // parity 0
    ws[OFF_C1 + blk * 256 + tid] = ac;
  } else if (blk == 64) {
    for (int g = tid; g < 1024; g += 256) {
      ws[OFF_BSUM0 + g] = bih0[g] + bhh0[g];
      ws[OFF_BSUM1 + g] = bih1[g] + bhh1[g];
    }
    for (int i = tid; i < 2048; i += 256) argkey[i] = 0ull;
  } else {
    const int base = (blk - 65) * 256 + tid;
    for (int i = base; i < 64 * 512; i += 15 * 256) key2[i] = 0ull;
    for (int i = base; i < NFLAGS; i += 15 * 256) {
      unsigned v = 0u;
      if (i >= F_ARG && i < F_ARG + 512 && (i - F_ARG) >= 400) v = 0xFFFFFFFFu;
      flags[i] = v;
    }
  }
}

// ---- K2: re-layout weights to [k4][1024 g][4 k] for coalesced dwordx4 GEMV loads ----
__global__ void lstm_transpose_kernel(const float* Wih0, const float* Whh0,
                                      const float* Wih1, const float* Whh1, float* ws) {
  __shared__ float t[64][65];
  const int blk = blockIdx.x, tid = threadIdx.x;
  const float* src; int dstoff; int C; int tile;
  if (blk < 128)      { src = Wih0; dstoff = OFF_W4IH0; C = 512; tile = blk; }
  else if (blk < 192) { src = Whh0; dstoff = OFF_W4HH0; C = 256; tile = blk - 128; }
  else if (blk < 256) { src = Wih1; dstoff = OFF_W4IH1; C = 256; tile = blk - 192; }
  else                { src = Whh1; dstoff = OFF_W4HH1; C = 256; tile = blk - 256; }
  const int tpr = C >> 6;
  const int r0 = (tile / tpr) << 6, c0 = (tile % tpr) << 6;  // r0: g-origin, c0: k-origin
  const int c = tid & 63, w = tid >> 6;
  for (int p = 0; p < 16; ++p) { int r = p * 4 + w; t[r][c] = src[(size_t)(r0 + r) * C + c0 + c]; }
  __syncthreads();
  float4* dst = (float4*)(ws + dstoff);
  const int g = tid & 63, kq = tid >> 6;
  for (int p = 0; p < 4; ++p) {
    const int k4l = p * 4 + kq;
    float4 v = make_float4(t[g][k4l * 4 + 0], t[g][k4l * 4 + 1],
                           t[g][k4l * 4 + 2], t[g][k4l * 4 + 3]);
    dst[(size_t)((c0 >> 2) + k4l) * 1024 + (r0 + g)] = v;
  }
}

// ---- K3: seed partA(0)=h0_init@Whh0^T, partB(0)=h1_init@Whh1^T ----
__global__ void lstm_parts_init_kernel(float* ws) {
  __shared__ float xp[8 * 256];
  const int blk = blockIdx.x, tid = threadIdx.x;
  const int isB = blk >= 32;
  const int idx = isB ? blk - 32 : blk;
  const int bg = idx >> 2, ps = idx & 3;
  const float* xsrc = ws + (isB ? OFF_H1 : OFF_H0);
  const float4* Wv = (const float4*)(ws + (isB ? OFF_W4HH1 : OFF_W4HH0));
  float* dst = ws + (isB ? OFF_PARTB : OFF_PARTA);
#pragma unroll
  for (int i = 0; i < 8; ++i) xp[i * 256 + tid] = xsrc[(bg * 8 + i) * 256 + tid];
  __syncthreads();
  const int gc = (tid >> 6) * 256 + ps * 64 + (tid & 63);
  float acc[8];
#pragma unroll
  for (int b = 0; b < 8; ++b) acc[b] = 0.f;
  for (int k4 = 0; k4 < 64; ++k4) {
    float4 wq = Wv[(size_t)k4 * 1024 + gc];
#pragma unroll
    for (int b = 0; b < 8; ++b) {
      float4 x = *(const float4*)&xp[b * 256 + k4 * 4];
      acc[b] = fmaf(wq.x, x.x, fmaf(wq.y, x.y, fmaf(wq.z, x.z, fmaf(wq.w, x.w, acc[b]))));
    }
  }
#pragma unroll
  for (int b = 0; b < 8; ++b) dst[(size_t)(bg * 8 + b) * 1024 + gc] = acc[b];
}

// ---- the persistent decode kernel ----
__global__ __launch_bounds__(256, 2) void lstm_decode_kernel(
    const float* __restrict__ emb, const float* __restrict__ Wout,
    const float* __restrict__ bout, const int* __restrict__ sosp,
    const int* __restrict__ eosp, float* __restrict__ ws,
    unsigned long long* __restrict__ argkey, unsigned long long* __restrict__ key2,
    unsigned* __restrict__ flags, int* __restrict__ out) {
  const int tid = threadIdx.x;
  const int blk = blockIdx.x;
  __shared__ int tok_s[64];
  __shared__ unsigned long long done_s;
  __shared__ int alldone_s;
  __shared__ union {
    float xa[8 * 64];                              // A: x slice [8b][64k]
    struct { float h0[8 * 256]; float gr[4 * 64 * 9]; } b;  // B
    float xp[8 * 256];                             // pA/pB x stage
    struct {                                       // D: Wout tile + h1, both swizzled
      float w[80 * 64];
      float h[64 * 64];
      unsigned long long red[4][64];
    } d;
    unsigned long long r2[256];                    // R scratch
  } sm;

  const bool isA = blk < 64;
  const bool isB = blk >= 64 && blk < 96;
  const bool isP = blk >= 96 && blk < 160;
  const int dIdx = isA ? blk : (blk >= 160 ? blk - 96 : -1);  // 0..399 or -1
  const int eos = *eosp;
  const int sos = *sosp;
  float c1reg[2];                                  // B: c1 strip lives here across steps

  for (int t = 0;; ++t) {
    const unsigned T = (unsigned)(t + 1);

    // ---------- A preamble: wait argmax(t-1), token/done bookkeeping ----------
    if (isA) {
      if (t == 0) {
        if (tid < 64) tok_s[tid] = sos;
        if (tid == 0) { done_s = 0ull; alldone_s = 0; }
      } else {
        if (tid < 64) {
          while (ld_cohu(flags + F_RED + tid * 32) < (unsigned)t)
            __builtin_amdgcn_s_sleep(2);
        }
        __syncthreads();
        if (tid < 64) {
          unsigned long long key = ld_coh64(&argkey[(((t - 1) & 3) * 64 + tid) * 8]);
          int v = (int)(~(unsigned)key);
          int outv = alldone_s ? 0 : v;
          if (blk == 0) out[tid * TSTEPS + (t - 1)] = outv;
          bool nd = (((done_s >> tid) & 1ull) != 0ull) || (outv == eos);
          unsigned long long m = __ballot(nd);
          if (tid == 0) { done_s = m; if (m == ~0ull) alldone_s = 1; }
          tok_s[tid] = outv;                       // emb row 0 is zeros -> pad ok
        }
      }
      __syncthreads();
    }
    if (t == TSTEPS) break;

    // ---------- A: emb-part gates0 partials (64 blocks = 8bg x 8ks, K=64) ----------
    if (isA) {
      const int bg = blk >> 3, ks = blk & 7;
      const int k = tid & 63;
#pragma unroll
      for (int i = 0; i < 2; ++i) {
        const int b = (tid >> 6) * 2 + i;
        sm.xa[b * 64 + k] = emb[(size_t)tok_s[bg * 8 + b] * 512 + ks * 64 + k];
      }
      __syncthreads();
      const float4* Wv = (const float4*)(ws + OFF_W4IH0);
      float acc[4][8];
#pragma unroll
      for (int q = 0; q < 4; ++q)
#pragma unroll
        for (int b = 0; b < 8; ++b) acc[q][b] = 0.f;
#pragma unroll 4
      for (int k4 = 0; k4 < 16; ++k4) {
        float4 wq[4];
#pragma unroll
        for (int q = 0; q < 4; ++q)
          wq[q] = Wv[(size_t)(ks * 16 + k4) * 1024 + q * 256 + tid];
#pragma unroll
        for (int b = 0; b < 8; ++b) {
          float4 x = *(const float4*)&sm.xa[b * 64 + k4 * 4];
#pragma unroll
          for (int q = 0; q < 4; ++q)
            acc[q][b] = fmaf(wq[q].x, x.x, fmaf(wq[q].y, x.y,
                        fmaf(wq[q].z, x.z, fmaf(wq[q].w, x.w, acc[q][b]))));
        }
      }
#pragma unroll
      for (int q = 0; q < 4; ++q)
#pragma unroll
        for (int b = 0; b < 8; ++b)
          st_coh(&ws[OFF_APART + (size_t)(ks * 64 + bg * 8 + b) * 1024 + q * 256 + tid],
                 acc[q][b]);
      post_u32(flags + F_CELL + bg * 32 + ks, T);
    }

    // ---------- B: fold gates0 -> h0/c0; Wih1 GEMV -> gates1 -> h1/c1 ----------
    if (isB) {
      const int bb = blk - 64, bg = bb >> 2, hq = bb & 3;
      unsigned* line = flags + F_CELL + bg * 32;
      if (tid < 64) {
        int idx = -1; unsigned tgt = 0;
        if (tid < 8)       { idx = tid;           tgt = T; }            // A slices
        else if (tid < 12) { idx = 8 + (tid - 8); tgt = (unsigned)t; }  // partA (prev step)
        else if (tid == 12){ idx = 12 + hq;       tgt = (unsigned)t; }  // partB strip
        for (;;) {
          unsigned v = tgt;
          if (idx >= 0) v = ld_cohu(line + idx);
          if (__all((int)(v >= tgt))) break;
          __builtin_amdgcn_s_sleep(2);
        }
      }
      __syncthreads();
      // fold full gates0 (redundant x4 across hq) -> full h0 in LDS; store own strip
      const int h = tid;
#pragma unroll
      for (int i = 0; i < 8; ++i) {
        const int b = bg * 8 + i;
        float gi = ws[OFF_BSUM0 + h]       + ld_coh(&ws[OFF_PARTA + (size_t)b * 1024 + h]);
        float gf = ws[OFF_BSUM0 + 256 + h] + ld_coh(&ws[OFF_PARTA + (size_t)b * 1024 + 256 + h]);
        float gg = ws[OFF_BSUM0 + 512 + h] + ld_coh(&ws[OFF_PARTA + (size_t)b * 1024 + 512 + h]);
        float go = ws[OFF_BSUM0 + 768 + h] + ld_coh(&ws[OFF_PARTA + (size_t)b * 1024 + 768 + h]);
#pragma unroll
        for (int s = 0; s < 8; ++s) {
          const float* gp = ws + OFF_APART + (size_t)(s * 64 + b) * 1024;
          gi += ld_coh(&gp[h]);       gf += ld_coh(&gp[256 + h]);
          gg += ld_coh(&gp[512 + h]); go += ld_coh(&gp[768 + h]);
        }
        float c  = ld_coh(&ws[OFF_C0 + (t & 1) * 16384 + b * 256 + h]);
        float cn = sigf(gf) * c + sigf(gi) * tanhf(gg);
        float hn = sigf(go) * tanhf(cn);
        sm.b.h0[i * 256 + h] = hn;
        if ((tid >> 6) == hq) {
          st_coh(&ws[OFF_H0 + b * 256 + h], hn);
          st_coh(&ws[OFF_C0 + ((t + 1) & 1) * 16384 + b * 256 + h], cn);
        }
      }
      post_u32(line + 16 + hq, T);   // h0 ready (drains stores; also syncs LDS h0)
      // gates1 strip GEMV: gc = qq*256 + hq*64 + j, K=256
      const int qq = tid >> 6, j = tid & 63;
      const int gc = qq * 256 + hq * 64 + j;
      const float4* Wv1 = (const float4*)(ws + OFF_W4IH1);
      float acc1[8];
#pragma unroll
      for (int b = 0; b < 8; ++b) acc1[b] = 0.f;
#pragma unroll 4
      for (int k4 = 0; k4 < 64; ++k4) {
        float4 wq = Wv1[(size_t)k4 * 1024 + gc];
#pragma unroll
        for (int b = 0; b < 8; ++b) {
          float4 x = *(const float4*)&sm.b.h0[b * 256 + k4 * 4];
          acc1[b] = fmaf(wq.x, x.x, fmaf(wq.y, x.y,
                    fmaf(wq.z, x.z, fmaf(wq.w, x.w, acc1[b]))));
        }
      }
#pragma unroll
      for (int b = 0; b < 8; ++b)
        acc1[b] += ld_coh(&ws[OFF_PARTB + (size_t)(bg * 8 + b) * 1024 + gc]) + ws[OFF_BSUM1 + gc];
#pragma unroll
      for (int b = 0; b < 8; ++b) sm.b.gr[(qq * 64 + j) * 9 + b] = acc1[b];
      __syncthreads();
      // h1/c1 for own strip (c1 in registers)
#pragma unroll
      for (int i2 = 0; i2 < 2; ++i2) {
        const int b2 = (tid >> 6) * 2 + i2;
        const int jj = tid & 63;
        float gi = sm.b.gr[(0 * 64 + jj) * 9 + b2];
        float gf = sm.b.gr[(1 * 64 + jj) * 9 + b2];
        float gg = sm.b.gr[(2 * 64 + jj) * 9 + b2];
        float go = sm.b.gr[(3 * 64 + jj) * 9 + b2];
        float c  = (t == 0) ? ws[OFF_C1 + (bg * 8 + b2) * 256 + hq * 64 + jj] : c1reg[i2];
        float cn = sigf(gf) * c + sigf(gi) * tanhf(gg);
        float hn = sigf(go) * tanhf(cn);
        c1reg[i2] = cn;
        st_coh(&ws[OFF_H1 + (bg * 8 + b2) * 256 + hq * 64 + jj], hn);
      }
      post_u32(flags + F_H1F + (bg * 4 + hq) * 32, T);
    }

    // ---------- parts (off critical path) + argmax reduce ----------
    if (isP) {
      const int pp = blk - 96;
      {
        const int isPB = pp >= 32;
        const int idx = isPB ? pp - 32 : pp;
        const int bg = idx >> 2, ps = idx & 3;
        // wait x ready
        if (tid < 4) {
          const unsigned* f = isPB ? (flags + F_H1F + (bg * 4 + tid) * 32)
                                   : (flags + F_CELL + bg * 32 + 16 + tid);
          while (ld_cohu(f) < T) __builtin_amdgcn_s_sleep(4);
        }
        __syncthreads();
        const float* xsrc = ws + (isPB ? OFF_H1 : OFF_H0);
#pragma unroll
        for (int i = 0; i < 8; ++i)
          sm.xp[i * 256 + tid] = ld_coh(&xsrc[(bg * 8 + i) * 256 + tid]);
        __syncthreads();
        const int gc = (tid >> 6) * 256 + ps * 64 + (tid & 63);
        const float4* Wv = (const float4*)(ws + (isPB ? OFF_W4HH1 : OFF_W4HH0));
        float* dst = ws + (isPB ? OFF_PARTB : OFF_PARTA);
        float acc[8];
#pragma unroll
        for (int b = 0; b < 8; ++b) acc[b] = 0.f;
#pragma unroll 4
        for (int k4 = 0; k4 < 64; ++k4) {
          float4 wq = Wv[(size_t)k4 * 1024 + gc];
#pragma unroll
          for (int b = 0; b < 8; ++b) {
            float4 x = *(const float4*)&sm.xp[b * 256 + k4 * 4];
            acc[b] = fmaf(wq.x, x.x, fmaf(wq.y, x.y,
                     fmaf(wq.z, x.z, fmaf(wq.w, x.w, acc[b]))));
          }
        }
#pragma unroll
        for (int b = 0; b < 8; ++b)
          st_coh(&dst[(size_t)(bg * 8 + b) * 1024 + gc], acc[b]);
        post_u32(flags + F_CELL + bg * 32 + (isPB ? 12 : 8) + ps, T);
      }
      // R: fold 400 per-block argmax keys for batch rb
      const int rb = pp;
      for (;;) {
        int ok = (ld_cohu(flags + F_ARG + tid) >= T) &&
                 (ld_cohu(flags + F_ARG + 256 + tid) >= T);
        if (__syncthreads_and(ok)) break;
        __builtin_amdgcn_s_sleep(4);
      }
      unsigned long long a  = ld_coh64(&key2[(size_t)rb * 512 + tid]);
      unsigned long long b2 = ld_coh64(&key2[(size_t)rb * 512 + 256 + tid]);
      sm.r2[tid] = a > b2 ? a : b2;
      __syncthreads();
      if (tid < 64) {
        unsigned long long v = sm.r2[tid];
        unsigned long long w1 = sm.r2[tid + 64];  v = v > w1 ? v : w1;
        w1 = sm.r2[tid + 128]; v = v > w1 ? v : w1;
        w1 = sm.r2[tid + 192]; v = v > w1 ? v : w1;
#pragma unroll
        for (int off = 32; off >= 1; off >>= 1) {
          unsigned long long o = __shfl_xor(v, off, 64);
          v = v > o ? v : o;
        }
        if (tid == 0) st_coh64(&argkey[((t & 3) * 64 + rb) * 8], v);
      }
      post_u32(flags + F_RED + rb * 32, T);
    }

    // ---------- D: logits (400 blocks x 80 vocab rows) + per-block argmax ----------
    if (dIdx >= 0) {
      const int d = dIdx;
      const int v_col = tid >> 4, b_row = tid & 15;
      float4 wpre[5];
#pragma unroll
      for (int p = 0; p < 5; ++p) {
        const int idx = p * 256 + tid, r = idx >> 4, cq = idx & 15;
        wpre[p] = *(const float4*)&Wout[(size_t)(d * 80 + r) * 256 + cq * 4];
      }
      if (tid < 64) {
        unsigned v = T;
        for (;;) {
          if (tid < 32) v = ld_cohu(flags + F_H1F + tid * 32);
          if (__all((int)(v >= T))) break;
          __builtin_amdgcn_s_sleep(8);
        }
      }
      __syncthreads();
      float4 hpre[4];
#pragma unroll
      for (int p = 0; p < 4; ++p) {
        const int idx = p * 256 + tid, r = idx >> 4, cq = idx & 15;
        const unsigned long long* hp = (const unsigned long long*)&ws[OFF_H1 + r * 256 + cq * 4];
        ((unsigned long long*)&hpre[p])[0] = ld_coh64(&hp[0]);
        ((unsigned long long*)&hpre[p])[1] = ld_coh64(&hp[1]);
      }
      float acc[5][4];
#pragma unroll
      for (int i = 0; i < 5; ++i)
#pragma unroll
        for (int j = 0; j < 4; ++j) acc[i][j] = 0.f;

      for (int kc = 0; kc < 4; ++kc) {
        __syncthreads();
#pragma unroll
        for (int p = 0; p < 5; ++p) {
          const int idx = p * 256 + tid, r = idx >> 4, cq = idx & 15;
          *(float4*)&sm.d.w[r * 64 + ((cq ^ (r & 15)) << 2)] = wpre[p];
        }
#pragma unroll
        for (int p = 0; p < 4; ++p) {
          const int idx = p * 256 + tid, r = idx >> 4, cq = idx & 15;
          *(float4*)&sm.d.h[r * 64 + ((cq ^ ((r >> 2) & 15)) << 2)] = hpre[p];
        }
        __syncthreads();
        if (kc < 3) {
#pragma unroll
          for (int p = 0; p < 5; ++p) {
            const int idx = p * 256 + tid, r = idx >> 4, cq = idx & 15;
            wpre[p] = *(const float4*)&Wout[(size_t)(d * 80 + r) * 256 + (kc + 1) * 64 + cq * 4];
          }
#pragma unroll
          for (int p = 0; p < 4; ++p) {
            const int idx = p * 256 + tid, r = idx >> 4, cq = idx & 15;
            const unsigned long long* hp =
                (const unsigned long long*)&ws[OFF_H1 + r * 256 + (kc + 1) * 64 + cq * 4];
            ((unsigned long long*)&hpre[p])[0] = ld_coh64(&hp[0]);
            ((unsigned long long*)&hpre[p])[1] = ld_coh64(&hp[1]);
          }
        }
#pragma unroll 4
        for (int k4 = 0; k4 < 16; ++k4) {
          float4 wv[5], hv[4];
#pragma unroll
          for (int vi = 0; vi < 5; ++vi) {
            const int rr = v_col * 5 + vi;
            wv[vi] = *(const float4*)&sm.d.w[rr * 64 + ((k4 ^ (rr & 15)) << 2)];
          }
#pragma unroll
          for (int j = 0; j < 4; ++j) {
            const int b = b_row * 4 + j;
            hv[j] = *(const float4*)&sm.d.h[b * 64 + ((k4 ^ b_row) << 2)];
          }
#pragma unroll
          for (int vi = 0; vi < 5; ++vi)
#pragma unroll
            for (int j = 0; j < 4; ++j)
              acc[vi][j] = fmaf(wv[vi].x, hv[j].x,
                           fmaf(wv[vi].y, hv[j].y,
                           fmaf(wv[vi].z, hv[j].z,
                           fmaf(wv[vi].w, hv[j].w, acc[vi][j]))));
        }
      }
      unsigned long long best[4];
#pragma unroll
      for (int j = 0; j < 4; ++j) {
        best[j] = 0ull;
#pragma unroll
        for (int vi = 0; vi < 5; ++vi) {
          const int v = d * 80 + v_col * 5 + vi;
          const float lg = acc[vi][j] + bout[v];
          unsigned u = __float_as_uint(lg);
          u = (u & 0x80000000u) ? ~u : (u | 0x80000000u);
          const unsigned long long key = ((unsigned long long)u << 32) | (unsigned)(~(unsigned)v);
          best[j] = best[j] > key ? best[j] : key;
        }
        unsigned long long o = __shfl_xor(best[j], 16, 64);
        best[j] = best[j] > o ? best[j] : o;
        o = __shfl_xor(best[j], 32, 64);
        best[j] = best[j] > o ? best[j] : o;
      }
      const int lane = tid & 63, wvi = tid >> 6;
      if ((lane >> 4) == 0) {
#pragma unroll
        for (int j = 0; j < 4; ++j) sm.d.red[wvi][(lane & 15) * 4 + j] = best[j];
      }
      __syncthreads();
      if (tid < 64) {
        unsigned long long m0 = sm.d.red[0][tid], m1 = sm.d.red[1][tid];
        unsigned long long m2 = sm.d.red[2][tid], m3 = sm.d.red[3][tid];
        unsigned long long ma = m0 > m1 ? m0 : m1;
        unsigned long long mb = m2 > m3 ? m2 : m3;
        unsigned long long mm = ma > mb ? ma : mb;
        st_coh64(&key2[(size_t)tid * 512 + d], mm);
      }
      post_u32(flags + F_ARG + d, T);
    }
  }
}

extern "C" void kernel_launch(void* const* d_in, const int* in_sizes, int n_in,
                              void* d_out, int out_size, void* d_ws, size_t ws_size,
                              hipStream_t stream) {
  const float* enc  = (const float*)d_in[0];
  const float* emb  = (const float*)d_in[1];
  const float* Wh   = (const float*)d_in[2];
  const float* bh   = (const float*)d_in[3];
  const float* Wc   = (const float*)d_in[4];
  const float* bc   = (const float*)d_in[5];
  const float* Wih0 = (const float*)d_in[6];
  const float* Whh0 = (const float*)d_in[7];
  const float* bih0 = (const float*)d_in[8];
  const float* bhh0 = (const float*)d_in[9];
  const float* Wih1 = (const float*)d_in[10];
  const float* Whh1 = (const float*)d_in[11];
  const float* bih1 = (const float*)d_in[12];
  const float* bhh1 = (const float*)d_in[13];
  const float* Wout = (const float*)d_in[14];
  const float* bout = (const float*)d_in[15];
  const int* sosp   = (const int*)d_in[16];
  const int* eosp   = (const int*)d_in[17];

  float* ws = (float*)d_ws;
  char* base = (char*)d_ws + (size_t)OFF_FLOAT_END * 4;
  unsigned long long* argkey = (unsigned long long*)base;            // 16384 B
  unsigned long long* key2   = (unsigned long long*)(base + 16384);  // 262144 B
  unsigned* flags            = (unsigned*)(base + 16384 + 262144);   // 15360 B
  int* out = (int*)d_out;

  lstm_init_kernel<<<80, NTHR, 0, stream>>>(enc, Wh, bh, Wc, bc, bih0, bhh0,
                                            bih1, bhh1, ws, argkey, key2, flags);
  lstm_transpose_kernel<<<320, NTHR, 0, stream>>>(Wih0, Whh0, Wih1, Whh1, ws);
  lstm_parts_init_kernel<<<64, NTHR, 0, stream>>>(ws);
  lstm_decode_kernel<<<NBLK, NTHR, 0, stream>>>(emb, Wout, bout, sosp, eosp,
                                                ws, argkey, key2, flags, out);
}

// Round 8
// 3219.535 us; speedup vs baseline: 2.3821x; 2.3821x over previous
//
#include <hip/hip_runtime.h>
#include <math.h>

#define TSTEPS 48
#define NCELL 32
#define ND 224
#define NBLK (NCELL + ND)

// ---------------- ws float offsets ----------------
#define OFF_W0T   0            // [2 hh][128 k4][512 gc] float4 (Wih0 re-layout)
#define OFF_W1T   524288       // [2][64][512] float4 (Wih1)
#define OFF_WH0T  786432       // [2][64][512] float4 (Whh0)
#define OFF_WH1T  1048576      // [2][64][512] float4 (Whh1)
#define OFF_BS0   1310720      // [2 hh][512 gc]
#define OFF_BS1   1311744
#define OFF_HINIT 1312768      // [64][256]
#define OFF_CINIT 1329152
#define OFF_H0BUF 1345536      // [64][256]
#define OFF_H1BUF 1361920
#define OFF_FLOAT_END 1378304
// then: key2 u64[64][256] (131072 B), flags u32[12288] (49152 B)

#define FSTR 32
#define FL_H0F   0       // 32
#define FL_H1C   1024    // 32
#define FL_H1ALL 2048    // 32
#define FL_DFLAG 3072    // 224
#define FL_DMIR  10240   // 32
#define FL_TOK   11264   // 32
#define NFLAGU32 12288

typedef float f4v __attribute__((ext_vector_type(4)));

// ---- coherent accessors ----
__device__ __forceinline__ unsigned ld_cohu(const unsigned* p) {
  return __hip_atomic_load((unsigned*)p, __ATOMIC_RELAXED, __HIP_MEMORY_SCOPE_AGENT);
}
__device__ __forceinline__ void st_cohu(unsigned* p, unsigned v) {
  __hip_atomic_store(p, v, __ATOMIC_RELAXED, __HIP_MEMORY_SCOPE_AGENT);
}
__device__ __forceinline__ unsigned long long ld_coh64(const unsigned long long* p) {
  return __hip_atomic_load((unsigned long long*)p, __ATOMIC_RELAXED, __HIP_MEMORY_SCOPE_AGENT);
}
__device__ __forceinline__ void st_coh64(unsigned long long* p, unsigned long long v) {
  __hip_atomic_store(p, v, __ATOMIC_RELAXED, __HIP_MEMORY_SCOPE_AGENT);
}
// 16B coherent load (bypass L0+L2 -> IC), blocking
__device__ __forceinline__ float4 ldg_coh_f4(const float4* p) {
  f4v r;
  asm volatile("global_load_dwordx4 %0, %1, off sc0 sc1\n\ts_waitcnt vmcnt(0)"
               : "=v"(r) : "v"(p) : "memory");
  return make_float4(r.x, r.y, r.z, r.w);
}
// 4 x 16B coherent loads in flight, one wait
__device__ __forceinline__ void ldg_coh_f4x4(const float4* p0, const float4* p1,
                                             const float4* p2, const float4* p3,
                                             float4& a, float4& b, float4& c, float4& d) {
  f4v ra, rb, rc, rd;
  asm volatile(
      "global_load_dwordx4 %0, %4, off sc0 sc1\n\t"
      "global_load_dwordx4 %1, %5, off sc0 sc1\n\t"
      "global_load_dwordx4 %2, %6, off sc0 sc1\n\t"
      "global_load_dwordx4 %3, %7, off sc0 sc1\n\t"
      "s_waitcnt vmcnt(0)"
      : "=&v"(ra), "=&v"(rb), "=&v"(rc), "=&v"(rd)
      : "v"(p0), "v"(p1), "v"(p2), "v"(p3) : "memory");
  a = make_float4(ra.x, ra.y, ra.z, ra.w);
  b = make_float4(rb.x, rb.y, rb.z, rb.w);
  c = make_float4(rc.x, rc.y, rc.z, rc.w);
  d = make_float4(rd.x, rd.y, rd.z, rd.w);
}
// 16B coherent write-through store (fire and forget; drain_vm before flag post)
__device__ __forceinline__ void stg_coh_f4(float4* p, float4 v) {
  f4v t = {v.x, v.y, v.z, v.w};
  asm volatile("global_store_dwordx4 %0, %1, off sc0 sc1" :: "v"(p), "v"(t) : "memory");
}
__device__ __forceinline__ void drain_vm() {
  asm volatile("s_waitcnt vmcnt(0)" ::: "memory");
}
// non-temporal 16B load (streaming; don't pollute L2)
__device__ __forceinline__ float4 ldnt_f4(const float4* p) {
  f4v v = __builtin_nontemporal_load((const f4v*)p);
  return make_float4(v.x, v.y, v.z, v.w);
}
__device__ __forceinline__ float sigf(float x) { return 1.0f / (1.0f + expf(-x)); }
__device__ __forceinline__ unsigned long long u64max(unsigned long long a, unsigned long long b) {
  return a > b ? a : b;
}
__device__ __forceinline__ unsigned long long wmax64(unsigned long long k) {
#pragma unroll
  for (int off = 1; off < 64; off <<= 1) {
    unsigned long long o = __shfl_xor(k, off, 64);
    k = u64max(k, o);
  }
  return k;
}
__device__ __forceinline__ unsigned long long packkey(float lg, int v) {
  unsigned u = __float_as_uint(lg);
  u = (u & 0x80000000u) ? ~u : (u | 0x80000000u);
  return ((unsigned long long)u << 32) | (unsigned)(~(unsigned)v);
}
__device__ __forceinline__ float4 f4add(float4 a, float4 b) {
  return make_float4(a.x + b.x, a.y + b.y, a.z + b.z, a.w + b.w);
}

// ---------------- init kernels ----------------
__global__ void lstm_init_kernel(const float* enc, const float* Wh, const float* bh,
                                 const float* Wc, const float* bc,
                                 const float* bih0, const float* bhh0,
                                 const float* bih1, const float* bhh1,
                                 float* ws, unsigned long long* key2, unsigned* flags) {
  const int tid = threadIdx.x, blk = blockIdx.x;
  if (blk < 64) {
    __shared__ float el[256];
    el[tid] = enc[blk * 256 + tid];
    __syncthreads();
    const float4* el4 = (const float4*)el;
    const float4* wh4 = (const float4*)(Wh + tid * 256);
    const float4* wc4 = (const float4*)(Wc + tid * 256);
    float ah = bh[tid], ac = bc[tid];
#pragma unroll 4
    for (int f = 0; f < 64; ++f) {
      float4 x = el4[f], a = wh4[f], b = wc4[f];
      ah = fmaf(a.x, x.x, fmaf(a.y, x.y, fmaf(a.z, x.z, fmaf(a.w, x.w, ah))));
      ac = fmaf(b.x, x.x, fmaf(b.y, x.y, fmaf(b.z, x.z, fmaf(b.w, x.w, ac))));
    }
    ws[OFF_HINIT + blk * 256 + tid] = ah;
    ws[OFF_CINIT + blk * 256 + tid] = ac;
  } else if (blk == 64) {
    for (int g = tid; g < 1024; g += 256) {
      int hh = g >> 9, gc = g & 511;
      int row = (gc >> 7) * 256 + hh * 128 + (gc & 127);
      ws[OFF_BS0 + g] = bih0[row] + bhh0[row];
      ws[OFF_BS1 + g] = bih1[row] + bhh1[row];
    }
  } else {
    const int base = (blk - 65) * 256 + tid;  // 15 blocks, stride 3840
    for (int i = base; i < 64 * 256; i += 15 * 256) key2[i] = 0ull;
    for (int i = base; i < NFLAGU32; i += 15 * 256) flags[i] = 0u;
  }
}

// re-layout the 4 gate-weight matrices into [hh][k4][512 gc] float4
__global__ void lstm_relayout_kernel(const float* Wih0, const float* Whh0,
                                     const float* Wih1, const float* Whh1, float* ws) {
  const int gid = blockIdx.x * 256 + threadIdx.x;
  const int gstr = 256 * 256;
  const float* srcs[4] = {Wih0, Wih1, Whh0, Whh1};
  const int dsts[4] = {OFF_W0T, OFF_W1T, OFF_WH0T, OFF_WH1T};
  const int k4tot[4] = {128, 64, 64, 64};
  for (int s = 0; s < 4; ++s) {
    const int n = 2 * k4tot[s] * 512;
    float4* dst = (float4*)(ws + dsts[s]);
    const float4* src = (const float4*)srcs[s];
    for (int e = gid; e < n; e += gstr) {
      int hh = e / (k4tot[s] * 512);
      int r = e - hh * k4tot[s] * 512;
      int k4 = r / 512, gc = r - k4 * 512;
      int row = (gc >> 7) * 256 + hh * 128 + (gc & 127);
      dst[e] = src[(size_t)row * k4tot[s] + k4];
    }
  }
}

// ---------------- decode: shared-memory layouts ----------------
struct CellSm {
  float x[4 * 512];
  float4 part[1024];
  float4 r0res[512];
  float4 r1res[512];
  float h0[4 * 256];
  float h1[4 * 256];
  float c0[4 * 128];
  float c1[4 * 128];
  int tok[4];
  unsigned fm[32];
  unsigned long long fred[16];
  int done4;
  int alldone;
};
struct DSm {
  float w[16 * 144 * 4];        // [k4][144 rows][4]
  float h[64 * 68];             // [b][68] (padded, 16B-aligned rows)
  unsigned long long kr[128];   // [b][wavehalf]
  unsigned long long epi[16 * 64];
};
union Smem { CellSm c; DSm d; };

// GEMV half: thread (gc = tid&511, kh = tid>>9) accumulates its K-half for 4 batches.
template <int K4H>
__device__ __forceinline__ void gemv_half(const float4* __restrict__ W,
                                          const float* __restrict__ xl, int xstride,
                                          float4* __restrict__ part, int tid) {
  const int kh = tid >> 9;
  float a0 = 0.f, a1 = 0.f, a2 = 0.f, a3 = 0.f;
  const float4* wp = W + (size_t)(kh * K4H) * 512 + (tid & 511);
  const float* x0 = xl + kh * K4H * 4;
#pragma unroll 8
  for (int i = 0; i < K4H; ++i) {
    float4 w = wp[(size_t)i * 512];
    float4 xa = *(const float4*)(x0 + i * 4);
    float4 xb = *(const float4*)(x0 + xstride + i * 4);
    float4 xc = *(const float4*)(x0 + 2 * xstride + i * 4);
    float4 xd = *(const float4*)(x0 + 3 * xstride + i * 4);
    a0 = fmaf(w.x, xa.x, fmaf(w.y, xa.y, fmaf(w.z, xa.z, fmaf(w.w, xa.w, a0))));
    a1 = fmaf(w.x, xb.x, fmaf(w.y, xb.y, fmaf(w.z, xb.z, fmaf(w.w, xb.w, a1))));
    a2 = fmaf(w.x, xc.x, fmaf(w.y, xc.y, fmaf(w.z, xc.z, fmaf(w.w, xc.w, a2))));
    a3 = fmaf(w.x, xd.x, fmaf(w.y, xd.y, fmaf(w.z, xd.z, fmaf(w.w, xd.w, a3))));
  }
  part[tid] = make_float4(a0, a1, a2, a3);
}

__device__ __forceinline__ void cellfold(const float4* part, const float4* rres,
                                         const float* bs, float* cst, float* hst,
                                         int hh, int tid) {
  if (tid < 512) {
    int jj = tid & 127, b = tid >> 7;
    float g[4];
#pragma unroll
    for (int q = 0; q < 4; ++q) {
      int gc = q * 128 + jj;
      g[q] = ((const float*)&part[gc])[b] + ((const float*)&part[512 + gc])[b] +
             ((const float*)&rres[gc])[b] + bs[gc];
    }
    float c = cst[b * 128 + jj];
    float cn = sigf(g[1]) * c + sigf(g[0]) * tanhf(g[2]);
    float hn = sigf(g[3]) * tanhf(cn);
    cst[b * 128 + jj] = cn;
    hst[b * 256 + hh * 128 + jj] = hn;
  }
}

__global__ __launch_bounds__(1024, 4) void lstm_decode_kernel(
    const float* __restrict__ emb, const float* __restrict__ Wout,
    const float* __restrict__ bout, const int* __restrict__ sosp,
    const int* __restrict__ eosp, float* __restrict__ ws,
    unsigned long long* __restrict__ key2, unsigned* __restrict__ flags,
    int* __restrict__ out) {
  const int tid = threadIdx.x;
  const int blk = blockIdx.x;
  __shared__ Smem sm;
  const int eos = *eosp;
  const int sos = *sosp;
  float4* h0b4 = (float4*)(ws + OFF_H0BUF);
  float4* h1b4 = (float4*)(ws + OFF_H1BUF);

  if (blk < NCELL) {
    // ======================= CELL block =======================
    const int bg = blk >> 1, hh = blk & 1, ph = 1 - hh;
    const float4* W0 = (const float4*)(ws + OFF_W0T) + (size_t)hh * 128 * 512;
    const float4* W1 = (const float4*)(ws + OFF_W1T) + (size_t)hh * 64 * 512;
    const float4* WH0 = (const float4*)(ws + OFF_WH0T) + (size_t)hh * 64 * 512;
    const float4* WH1 = (const float4*)(ws + OFF_WH1T) + (size_t)hh * 64 * 512;
    const float* bs0 = ws + OFF_BS0 + hh * 512;
    const float* bs1 = ws + OFF_BS1 + hh * 512;

    // t=0 state seed
    {
      int b = tid >> 8, k = tid & 255;
      float hv = ws[OFF_HINIT + (bg * 4 + b) * 256 + k];
      sm.c.h0[b * 256 + k] = hv;
      sm.c.h1[b * 256 + k] = hv;
    }
    if (tid < 512) {
      int b = tid >> 7, jj = tid & 127;
      float cv = ws[OFF_CINIT + (bg * 4 + b) * 256 + hh * 128 + jj];
      sm.c.c0[b * 128 + jj] = cv;
      sm.c.c1[b * 128 + jj] = cv;
    }
    if (tid < 4) sm.c.tok[tid] = sos;
    if (tid == 0) { sm.c.done4 = 0; sm.c.alldone = 0; }
    __syncthreads();
    // seed R0res/R1res from init states
    gemv_half<32>(WH0, sm.c.h0, 256, sm.c.part, tid);
    __syncthreads();
    if (tid < 512) sm.c.r0res[tid] = f4add(sm.c.part[tid], sm.c.part[512 + tid]);
    __syncthreads();
    gemv_half<32>(WH1, sm.c.h1, 256, sm.c.part, tid);
    __syncthreads();
    if (tid < 512) sm.c.r1res[tid] = f4add(sm.c.part[tid], sm.c.part[512 + tid]);
    __syncthreads();

    for (int t = 0; t < TSTEPS; ++t) {
      const unsigned T = (unsigned)(t + 1);
      // ---- E = Wih0(half) @ emb[tok] ----
      if (tid < 512) {
        int b = tid >> 7, j = tid & 127;
        ((float4*)sm.c.x)[b * 128 + j] = ((const float4*)emb)[(size_t)sm.c.tok[b] * 128 + j];
      }
      __syncthreads();
      gemv_half<64>(W0, sm.c.x, 512, sm.c.part, tid);
      __syncthreads();
      cellfold(sm.c.part, sm.c.r0res, bs0, sm.c.c0, sm.c.h0, hh, tid);
      __syncthreads();
      // post own h0 half, exchange with partner
      if (tid < 128) {
        int b = tid >> 5, j = tid & 31;
        float4 v = *(float4*)&sm.c.h0[b * 256 + hh * 128 + j * 4];
        stg_coh_f4(h0b4 + (bg * 4 + b) * 64 + hh * 32 + j, v);
      }
      drain_vm();
      __syncthreads();
      if (tid == 0) {
        st_cohu(flags + FL_H0F + blk * FSTR, T);
        while (ld_cohu(flags + FL_H0F + (blk ^ 1) * FSTR) < T) __builtin_amdgcn_s_sleep(1);
      }
      __syncthreads();
      if (tid < 128) {
        int b = tid >> 5, j = tid & 31;
        float4 v = ldg_coh_f4(h0b4 + (bg * 4 + b) * 64 + ph * 32 + j);
        *(float4*)&sm.c.h0[b * 256 + ph * 128 + j * 4] = v;
      }
      __syncthreads();
      // ---- G1 = Wih1(half) @ h0 ----
      gemv_half<32>(W1, sm.c.h0, 256, sm.c.part, tid);
      __syncthreads();
      cellfold(sm.c.part, sm.c.r1res, bs1, sm.c.c1, sm.c.h1, hh, tid);
      __syncthreads();
      // post h1 half + flag; relay all-ready to D
      if (tid < 128) {
        int b = tid >> 5, j = tid & 31;
        float4 v = *(float4*)&sm.c.h1[b * 256 + hh * 128 + j * 4];
        stg_coh_f4(h1b4 + (bg * 4 + b) * 64 + hh * 32 + j, v);
      }
      drain_vm();
      __syncthreads();
      if (tid == 0) st_cohu(flags + FL_H1C + blk * FSTR, T);
      if (tid < 64) {
        unsigned v = T;
        for (;;) {
          if (tid < 32) v = ld_cohu(flags + FL_H1C + tid * FSTR);
          if (__all((int)(v >= T))) break;
          __builtin_amdgcn_s_sleep(1);
        }
      }
      __syncthreads();
      if (tid == 0) st_cohu(flags + FL_H1ALL + blk * FSTR, T);
      // read partner h1 half (for R1)
      if (tid < 128) {
        int b = tid >> 5, j = tid & 31;
        float4 v = ldg_coh_f4(h1b4 + (bg * 4 + b) * 64 + ph * 32 + j);
        *(float4*)&sm.c.h1[b * 256 + ph * 128 + j * 4] = v;
      }
      __syncthreads();
      // ---- off-path: masks from step t-1 (for alldone) ----
      if (t > 0) {
        if (tid < 64) {
          unsigned tgt = (unsigned)t << 8;
          unsigned got = tgt;
          for (;;) {
            if (tid < 32) got = ld_cohu(flags + FL_TOK + tid * FSTR);
            if (__all((int)(got >= tgt))) break;
            __builtin_amdgcn_s_sleep(2);
          }
          if (tid < 32) sm.c.fm[tid] = got & 0xFFu;
        }
        __syncthreads();
        if (tid < 64) {
          int ok = 1;
          if (tid < 32) ok = (sm.c.fm[tid] == 0xFu);
          int all = __all(ok);
          if (tid == 0) sm.c.alldone = all;
        }
        __syncthreads();
      }
      // ---- off-path: R0/R1 for next step ----
      gemv_half<32>(WH0, sm.c.h0, 256, sm.c.part, tid);
      __syncthreads();
      if (tid < 512) sm.c.r0res[tid] = f4add(sm.c.part[tid], sm.c.part[512 + tid]);
      __syncthreads();
      gemv_half<32>(WH1, sm.c.h1, 256, sm.c.part, tid);
      __syncthreads();
      if (tid < 512) sm.c.r1res[tid] = f4add(sm.c.part[tid], sm.c.part[512 + tid]);
      __syncthreads();
      // ---- D-completion mirror ----
      if (tid < 64) {
        unsigned v = T;
        for (;;) {
          if (tid < 7) v = ld_cohu(flags + FL_DFLAG + (blk * 7 + tid) * FSTR);
          if (__all((int)(v >= T))) break;
          __builtin_amdgcn_s_sleep(4);
        }
      }
      __syncthreads();
      if (tid == 0) st_cohu(flags + FL_DMIR + blk * FSTR, T);
      if (tid < 64) {
        unsigned v = T;
        for (;;) {
          if (tid < 32) v = ld_cohu(flags + FL_DMIR + tid * FSTR);
          if (__all((int)(v >= T))) break;
          __builtin_amdgcn_s_sleep(2);
        }
      }
      __syncthreads();
      // ---- argmax fold for own 4 batches ----
      {
        int bb = tid >> 8, i = tid & 255;
        unsigned long long k = ld_coh64(key2 + (size_t)(bg * 4 + bb) * 256 + i);
        k = wmax64(k);
        if ((tid & 63) == 0) sm.c.fred[tid >> 6] = k;
      }
      __syncthreads();
      if (tid < 4) {
        int bb = tid;
        unsigned long long m = u64max(u64max(sm.c.fred[bb * 4], sm.c.fred[bb * 4 + 1]),
                                      u64max(sm.c.fred[bb * 4 + 2], sm.c.fred[bb * 4 + 3]));
        int v = (int)(~(unsigned)m);
        int outv = sm.c.alldone ? 0 : v;
        out[(bg * 4 + bb) * TSTEPS + t] = outv;
        int nd = ((sm.c.done4 >> bb) & 1) | (outv == eos ? 1 : 0);
        sm.c.tok[bb] = outv;
        sm.c.fm[bb] = (unsigned)nd;
      }
      __syncthreads();
      if (tid == 0) {
        int mask = (int)(sm.c.fm[0] | (sm.c.fm[1] << 1) | (sm.c.fm[2] << 2) | (sm.c.fm[3] << 3));
        sm.c.done4 = mask;
        if (t < TSTEPS - 1)
          st_cohu(flags + FL_TOK + blk * FSTR, ((unsigned)(t + 1) << 8) | (unsigned)mask);
      }
      __syncthreads();
    }
  } else {
    // ======================= D (logits) block =======================
    const int d = blk - NCELL;
    const int r0 = (d * 32000) / ND, r1 = ((d + 1) * 32000) / ND;
    const int rows = r1 - r0, nep = rows - 128;  // 14 or 15
    const int bg = tid >> 7, v = tid & 127;
    const int erow = tid >> 6, eb = tid & 63;
    const float4* Wout4 = (const float4*)Wout;
    const int nq = 144 * 16;

    for (int t = 0; t < TSTEPS; ++t) {
      const unsigned T = (unsigned)(t + 1);
      // prefetch kc=0 Wout chunk (token-independent)
      float4 wpre[3];
#pragma unroll
      for (int p = 0; p < 3; ++p) {
        int e = tid + p * 1024;
        if (e < nq) {
          int j = e / 144, r = e - j * 144;
          int rc = r0 + r; if (rc > 31999) rc = 31999;
          wpre[p] = ldnt_f4(Wout4 + (size_t)rc * 64 + j);
        } else wpre[p] = make_float4(0.f, 0.f, 0.f, 0.f);
      }
      // wait h1 ready (mirror line, 7 readers each)
      if (tid == 0) {
        while (ld_cohu(flags + FL_H1ALL + (d & 31) * FSTR) < T) __builtin_amdgcn_s_sleep(4);
      }
      __syncthreads();
      // read full h1 into registers (4 x 16B batched coherent loads)
      float4 hpre[4];
      {
        int b = tid >> 4, j = tid & 15;
        const float4* hp = (const float4*)h1b4 + (size_t)b * 64 + j;
        ldg_coh_f4x4(hp, hp + 16, hp + 32, hp + 48, hpre[0], hpre[1], hpre[2], hpre[3]);
      }
      float acc[8];
#pragma unroll
      for (int i = 0; i < 8; ++i) acc[i] = 0.f;
      float eacc = 0.f;

      for (int kc = 0; kc < 4; ++kc) {
        __syncthreads();
#pragma unroll
        for (int p = 0; p < 3; ++p) {
          int e = tid + p * 1024;
          if (e < nq) {
            int j = e / 144, r = e - j * 144;
            *(float4*)&sm.d.w[(j * 144 + r) * 4] = wpre[p];
          }
        }
        {
          int b = tid >> 4, j = tid & 15;
          *(float4*)&sm.d.h[b * 68 + j * 4] = hpre[kc];
        }
        __syncthreads();
        if (kc < 3) {
#pragma unroll
          for (int p = 0; p < 3; ++p) {
            int e = tid + p * 1024;
            if (e < nq) {
              int j = e / 144, r = e - j * 144;
              int rc = r0 + r; if (rc > 31999) rc = 31999;
              wpre[p] = ldnt_f4(Wout4 + (size_t)rc * 64 + (kc + 1) * 16 + j);
            }
          }
        }
        // main: row = r0 + v, 8 batches
#pragma unroll 4
        for (int k4 = 0; k4 < 16; ++k4) {
          float4 w4 = *(const float4*)&sm.d.w[(k4 * 144 + v) * 4];
#pragma unroll
          for (int bi = 0; bi < 8; ++bi) {
            float4 h4 = *(const float4*)&sm.d.h[(bg * 8 + bi) * 68 + k4 * 4];
            acc[bi] = fmaf(w4.x, h4.x, fmaf(w4.y, h4.y, fmaf(w4.z, h4.z, fmaf(w4.w, h4.w, acc[bi]))));
          }
        }
        // epilogue rows 128..rows-1 (wave-uniform branch)
        if (erow < nep) {
#pragma unroll 4
          for (int k4 = 0; k4 < 16; ++k4) {
            float4 w4 = *(const float4*)&sm.d.w[(k4 * 144 + 128 + erow) * 4];
            float4 h4 = *(const float4*)&sm.d.h[eb * 68 + k4 * 4];
            eacc = fmaf(w4.x, h4.x, fmaf(w4.y, h4.y, fmaf(w4.z, h4.z, fmaf(w4.w, h4.w, eacc))));
          }
        }
      }
      // ---- keys + block reduce ----
      {
        float bb_ = bout[r0 + v];
#pragma unroll
        for (int bi = 0; bi < 8; ++bi) {
          unsigned long long k = packkey(acc[bi] + bb_, r0 + v);
          k = wmax64(k);
          if ((tid & 63) == 0) sm.d.kr[(bg * 8 + bi) * 2 + (v >> 6)] = k;
        }
      }
      if (erow < nep) {
        sm.d.epi[erow * 64 + eb] = packkey(eacc + bout[r0 + 128 + erow], r0 + 128 + erow);
      } else {
        sm.d.epi[erow * 64 + eb] = 0ull;
      }
      __syncthreads();
      if (tid < 64) {
        unsigned long long m = u64max(sm.d.kr[tid * 2], sm.d.kr[tid * 2 + 1]);
#pragma unroll
        for (int er = 0; er < 15; ++er) m = u64max(m, sm.d.epi[er * 64 + tid]);
        st_coh64(key2 + (size_t)tid * 256 + d, m);
      }
      drain_vm();
      __syncthreads();
      if (tid == 0) st_cohu(flags + FL_DFLAG + d * FSTR, T);
    }
  }
}

extern "C" void kernel_launch(void* const* d_in, const int* in_sizes, int n_in,
                              void* d_out, int out_size, void* d_ws, size_t ws_size,
                              hipStream_t stream) {
  const float* enc  = (const float*)d_in[0];
  const float* emb  = (const float*)d_in[1];
  const float* Wh   = (const float*)d_in[2];
  const float* bh   = (const float*)d_in[3];
  const float* Wc   = (const float*)d_in[4];
  const float* bc   = (const float*)d_in[5];
  const float* Wih0 = (const float*)d_in[6];
  const float* Whh0 = (const float*)d_in[7];
  const float* bih0 = (const float*)d_in[8];
  const float* bhh0 = (const float*)d_in[9];
  const float* Wih1 = (const float*)d_in[10];
  const float* Whh1 = (const float*)d_in[11];
  const float* bih1 = (const float*)d_in[12];
  const float* bhh1 = (const float*)d_in[13];
  const float* Wout = (const float*)d_in[14];
  const float* bout = (const float*)d_in[15];
  const int* sosp   = (const int*)d_in[16];
  const int* eosp   = (const int*)d_in[17];

  float* ws = (float*)d_ws;
  char* base = (char*)d_ws + (size_t)OFF_FLOAT_END * 4;
  unsigned long long* key2 = (unsigned long long*)base;            // 131072 B
  unsigned* flags          = (unsigned*)(base + 131072);           // 49152 B
  int* out = (int*)d_out;

  lstm_init_kernel<<<80, 256, 0, stream>>>(enc, Wh, bh, Wc, bc, bih0, bhh0,
                                           bih1, bhh1, ws, key2, flags);
  lstm_relayout_kernel<<<256, 256, 0, stream>>>(Wih0, Whh0, Wih1, Whh1, ws);
  lstm_decode_kernel<<<NBLK, 1024, 0, stream>>>(emb, Wout, bout, sosp, eosp,
                                                ws, key2, flags, out);
}